// Round 3
// baseline (262.931 us; speedup 1.0000x reference)
//
#include <hip/hip_runtime.h>

#define NRAYS 16384
#define NS    128
#define NLEV  16
#define THASH 524288
#define BLK   256
#define MAXACT 48
#define MAXPTS (NRAYS*MAXACT)

// fp32 z_i exactly as np.linspace(2,6,128) fp32: step=fl32(4/127), z_i=fl32(2+fl32(i*step))
__device__ __forceinline__ float zval32(int i) {
  const float step = 4.0f / 127.0f;
  return __fadd_rn(2.0f, __fmul_rn((float)i, step));
}
__device__ __forceinline__ float pcoord(float o, float d, float z) {
  return __fadd_rn(o, __fmul_rn(d, z));
}

// ---------------- kernel 1: classify rays, SH encode, compact ----------------
__global__ void k_classify(const float* __restrict__ rays,
                           float* __restrict__ sh,
                           unsigned* __restrict__ counter,
                           unsigned* __restrict__ rbase,
                           unsigned* __restrict__ rn,
                           unsigned* __restrict__ plist) {
  int r = blockIdx.x * blockDim.x + threadIdx.x;
  if (r >= NRAYS) return;
  float ox = rays[6*r+0], oy = rays[6*r+1], oz = rays[6*r+2];
  float dx = rays[6*r+3], dy = rays[6*r+4], dz = rays[6*r+5];
  float x = dx, y = dy, z = dz;
  float xx = x*x, yy = y*y, zz = z*z, xy = x*y, yz = y*z, xz = x*z;
  float* shp = sh + 16*r;
  shp[0]  = 0.28209479177387814f;
  shp[1]  = -0.4886025119029199f * y;
  shp[2]  =  0.4886025119029199f * z;
  shp[3]  = -0.4886025119029199f * x;
  shp[4]  =  1.0925484305920792f * xy;
  shp[5]  = -1.0925484305920792f * yz;
  shp[6]  =  0.31539156525252005f * (2.0f*zz - xx - yy);
  shp[7]  = -1.0925484305920792f * xz;
  shp[8]  =  0.5462742152960396f * (xx - yy);
  shp[9]  = -0.5900435899266435f * y * (3.0f*xx - yy);
  shp[10] =  2.890611442640554f  * xy * z;
  shp[11] = -0.4570457994644658f * y * (4.0f*zz - xx - yy);
  shp[12] =  0.3731763325901154f * z * (2.0f*zz - 3.0f*xx - 3.0f*yy);
  shp[13] = -0.4570457994644658f * x * (4.0f*zz - xx - yy);
  shp[14] =  1.445305721320277f  * z * (xx - yy);
  shp[15] = -0.5900435899266435f * x * (xx - 3.0f*yy);
  // fp32 in-box prefix count (box convex, o inside => in-box samples are a prefix)
  int n = 0;
  for (int i = 0; i < NS; ++i) {
    float zi = zval32(i);
    float px = pcoord(ox, dx, zi);
    float py = pcoord(oy, dy, zi);
    float pz = pcoord(oz, dz, zi);
    bool in = (px >= -1.5f) && (px <= 1.5f) && (py >= -1.5f) && (py <= 1.5f)
           && (pz >= -1.5f) && (pz <= 1.5f);
    if (!in) break;
    ++n;
  }
  unsigned base = atomicAdd(counter, (unsigned)n);
  rbase[r] = base;
  rn[r]    = (unsigned)n;
  for (int i = 0; i < n; ++i) plist[base + i] = (unsigned)(r*NS + i);
}

// ---------------- kernel 2: hash encode + MLPs on compacted points ----------------
template<int IN, int OUT, bool RELU>
__device__ __forceinline__ void mlp_layer(const float* __restrict__ W, float* act, int t) {
  float acc[OUT];
#pragma unroll
  for (int j = 0; j < OUT; ++j) acc[j] = 0.0f;
#pragma unroll 4
  for (int k = 0; k < IN; ++k) {
    float a = act[k*BLK + t];
#pragma unroll
    for (int j = 0; j < OUT; ++j) acc[j] = fmaf(a, W[k*OUT + j], acc[j]);
  }
#pragma unroll
  for (int j = 0; j < OUT; ++j) act[j*BLK + t] = RELU ? fmaxf(acc[j], 0.0f) : acc[j];
}

__global__ __launch_bounds__(BLK)
void k_mlp(const float* __restrict__ rays,
           const float* __restrict__ tables,
           const float* __restrict__ w_s0, const float* __restrict__ w_s1,
           const float* __restrict__ w_s2, const float* __restrict__ w_c0,
           const float* __restrict__ w_c1, const float* __restrict__ w_c2,
           const float* __restrict__ w_c3,
           const float* __restrict__ sh,
           const unsigned* __restrict__ counter,
           const unsigned* __restrict__ plist,
           float4* __restrict__ results) {
  __shared__ float act[64*BLK];   // 64 KiB: per-thread private 64-float column
  const int t = threadIdx.x;
  unsigned s = blockIdx.x * BLK + t;
  unsigned count = *counter;
  if (s >= count) return;
  unsigned pid = plist[s];
  int r = (int)(pid >> 7);
  int i = (int)(pid & 127u);
  float ox = rays[6*r+0], oy = rays[6*r+1], oz = rays[6*r+2];
  float dx = rays[6*r+3], dy = rays[6*r+4], dz = rays[6*r+5];
  float zi = zval32(i);
  float px = pcoord(ox, dx, zi);
  float py = pcoord(oy, dy, zi);
  float pz = pcoord(oz, dz, zi);
  float xcx = fminf(fmaxf(px, -1.5f), 1.5f);
  float xcy = fminf(fmaxf(py, -1.5f), 1.5f);
  float xcz = fminf(fmaxf(pz, -1.5f), 1.5f);
  const float RESF[NLEV] = {16.f,20.f,25.f,32.f,40.f,50.f,64.f,80.f,
                            101.f,128.f,161.f,203.f,256.f,322.f,406.f,512.f};
#pragma unroll
  for (int l = 0; l < NLEV; ++l) {
    const float grid = 3.0f / RESF[l];
    float bfx = floorf(__fdiv_rn(__fadd_rn(xcx, 1.5f), grid));
    float bfy = floorf(__fdiv_rn(__fadd_rn(xcy, 1.5f), grid));
    float bfz = floorf(__fdiv_rn(__fadd_rn(xcz, 1.5f), grid));
    float vmx = __fadd_rn(__fmul_rn(bfx, grid), -1.5f);
    float vmy = __fadd_rn(__fmul_rn(bfy, grid), -1.5f);
    float vmz = __fadd_rn(__fmul_rn(bfz, grid), -1.5f);
    float wx = __fdiv_rn(__fsub_rn(xcx, vmx), grid);
    float wy = __fdiv_rn(__fsub_rn(xcy, vmy), grid);
    float wz = __fdiv_rn(__fsub_rn(xcz, vmz), grid);
    unsigned cx0 = (unsigned)(int)bfx, cy0 = (unsigned)(int)bfy, cz0 = (unsigned)(int)bfz;
    unsigned cx1 = cx0 + 1u, cy1 = cy0 + 1u, cz1 = cz0 + 1u;
    unsigned hy0 = cy0*2654435761u, hy1 = cy1*2654435761u;
    unsigned hz0 = cz0*805459861u,  hz1 = cz1*805459861u;
    const float2* tb = (const float2*)tables + (size_t)l*THASH;
    float2 e000 = tb[(cx0^hy0^hz0)&(THASH-1)];
    float2 e001 = tb[(cx0^hy0^hz1)&(THASH-1)];
    float2 e010 = tb[(cx0^hy1^hz0)&(THASH-1)];
    float2 e011 = tb[(cx0^hy1^hz1)&(THASH-1)];
    float2 e100 = tb[(cx1^hy0^hz0)&(THASH-1)];
    float2 e101 = tb[(cx1^hy0^hz1)&(THASH-1)];
    float2 e110 = tb[(cx1^hy1^hz0)&(THASH-1)];
    float2 e111 = tb[(cx1^hy1^hz1)&(THASH-1)];
    float iwx = 1.f-wx, iwy = 1.f-wy, iwz = 1.f-wz;
    float c00a = e000.x*iwx + e100.x*wx, c00b = e000.y*iwx + e100.y*wx;
    float c01a = e001.x*iwx + e101.x*wx, c01b = e001.y*iwx + e101.y*wx;
    float c10a = e010.x*iwx + e110.x*wx, c10b = e010.y*iwx + e110.y*wx;
    float c11a = e011.x*iwx + e111.x*wx, c11b = e011.y*iwx + e111.y*wx;
    float c0a = c00a*iwy + c10a*wy, c0b = c00b*iwy + c10b*wy;
    float c1a = c01a*iwy + c11a*wy, c1b = c01b*iwy + c11b*wy;
    act[(2*l+0)*BLK + t] = c0a*iwz + c1a*wz;
    act[(2*l+1)*BLK + t] = c0b*iwz + c1b*wz;
  }
  // sigma MLP: 32 -> 64 -> 64 -> 16
  mlp_layer<32,64,true >(w_s0, act, t);
  mlp_layer<64,64,true >(w_s1, act, t);
  mlp_layer<64,16,false>(w_s2, act, t);
  float sigma = act[0*BLK + t];
  float geo[15];
#pragma unroll
  for (int m = 0; m < 15; ++m) geo[m] = act[(1+m)*BLK + t];
  // color MLP input: SH(16) ++ geo(15)
  const float* shp = sh + 16*r;
#pragma unroll
  for (int k = 0; k < 16; ++k) act[k*BLK + t] = shp[k];
#pragma unroll
  for (int m = 0; m < 15; ++m) act[(16+m)*BLK + t] = geo[m];
  mlp_layer<31,64,true >(w_c0, act, t);
  mlp_layer<64,64,true >(w_c1, act, t);
  mlp_layer<64,64,true >(w_c2, act, t);
  mlp_layer<64,3, false>(w_c3, act, t);
  // store raw logits; sigmoid happens in fp64 in k_comp
  float4 res;
  res.x = sigma;
  res.y = act[0*BLK + t];
  res.z = act[1*BLK + t];
  res.w = act[2*BLK + t];
  results[s] = res;
}

// ---------------- kernel 3: per-ray volume rendering composite (fp64) ----------------
// The loss path amplifies alpha errors by |log p|+1 ~ 12 and alpha = 1-exp(-x)
// at x~3e-6 loses ~2% relative per fp32 ulp. fp64 here kills that error class.
__global__ void k_comp(const float* __restrict__ rays,
                       const unsigned* __restrict__ rbase,
                       const unsigned* __restrict__ rn,
                       const float4* __restrict__ results,
                       float* __restrict__ out) {
  int r = blockIdx.x * blockDim.x + threadIdx.x;
  if (r >= NRAYS) return;
  double dx = (double)rays[6*r+3], dy = (double)rays[6*r+4], dz = (double)rays[6*r+5];
  double dnorm = sqrt(dx*dx + dy*dy + dz*dz);
  int n = (int)rn[r];
  unsigned base = rbase[r];
  const double step = 4.0/127.0;
  const double diststep = step * dnorm;   // n<=47<127: never the 1e10 tail
  double S = 0.0, ch0 = 0.0, ch1 = 0.0, ch2 = 0.0, dep = 0.0, trans = 1.0;
  for (int i = 0; i < n; ++i) {
    float4 rs = results[base + i];
    double z = 2.0 + (double)i*step;
    double sg = fmax((double)rs.x, 0.0);
    double alpha = 1.0 - exp(-sg*diststep);
    double w = alpha * trans;
    trans = trans * (1.0 - alpha + 1e-10);
    double s0 = 1.0/(1.0 + exp(-(double)rs.y));
    double s1 = 1.0/(1.0 + exp(-(double)rs.z));
    double s2 = 1.0/(1.0 + exp(-(double)rs.w));
    S += w; ch0 += w*s0; ch1 += w*s1; ch2 += w*s2; dep += w*z;
  }
  double rem  = 1.0 - S + 1e-6;
  double Stot = S + rem;
  double loss = 0.0, trans2 = 1.0;
  for (int i = 0; i < n; ++i) {
    float4 rs = results[base + i];
    double sg = fmax((double)rs.x, 0.0);
    double alpha = 1.0 - exp(-sg*diststep);
    double w = alpha * trans2;
    trans2 = trans2 * (1.0 - alpha + 1e-10);
    double p = w / Stot;
    loss += p * log(fmax(p, 1e-37));
  }
  double pl = rem / Stot;
  loss += pl * log(fmax(pl, 1e-37));
  out[3*r+0] = (float)ch0; out[3*r+1] = (float)ch1; out[3*r+2] = (float)ch2;
  out[3*NRAYS + r] = (float)dep;
  out[4*NRAYS + r] = (float)(-loss);
}

// ---------------- launch ----------------
extern "C" void kernel_launch(void* const* d_in, const int* in_sizes, int n_in,
                              void* d_out, int out_size, void* d_ws, size_t ws_size,
                              hipStream_t stream) {
  const float* rays   = (const float*)d_in[0];
  const float* tables = (const float*)d_in[1];
  const float* ws0    = (const float*)d_in[2];
  const float* ws1    = (const float*)d_in[3];
  const float* ws2    = (const float*)d_in[4];
  const float* wc0    = (const float*)d_in[5];
  const float* wc1    = (const float*)d_in[6];
  const float* wc2    = (const float*)d_in[7];
  const float* wc3    = (const float*)d_in[8];

  char* ws = (char*)d_ws;
  unsigned* counter = (unsigned*)ws;
  unsigned* rbase   = (unsigned*)(ws + 256);
  unsigned* rn      = (unsigned*)(ws + 256 + 65536);
  float*    sh      = (float*)  (ws + 256 + 131072);
  float4*   results = (float4*) (ws + 1179904);                  // 256+131072+1048576
  unsigned* plist   = (unsigned*)(ws + 1179904 + (size_t)MAXPTS*16);

  hipMemsetAsync(counter, 0, 4, stream);
  k_classify<<<NRAYS/256, 256, 0, stream>>>(rays, sh, counter, rbase, rn, plist);
  k_mlp<<<MAXPTS/BLK, BLK, 0, stream>>>(rays, tables, ws0, ws1, ws2,
                                        wc0, wc1, wc2, wc3, sh, counter, plist, results);
  k_comp<<<NRAYS/256, 256, 0, stream>>>(rays, rbase, rn, results, (float*)d_out);
}

// Round 4
// 185.417 us; speedup vs baseline: 1.4181x; 1.4181x over previous
//
#include <hip/hip_runtime.h>

#define NRAYS 16384
#define NLEV  16
#define THASH 524288
#define MAXACT 48
#define MAXPTS (NRAYS*MAXACT)
#define MBLK  512      // k_mlp: 8 waves
#define MGRID 1024     // persistent grid (4 blocks/CU)

// fp32 z_i exactly as np.linspace(2,6,128) fp32: z_i = fl32(2 + fl32(i*step))
__device__ __forceinline__ float zval32(int i) {
  const float step = 4.0f / 127.0f;
  return __fadd_rn(2.0f, __fmul_rn((float)i, step));
}
__device__ __forceinline__ float pcoord(float o, float d, float z) {
  return __fadd_rn(o, __fmul_rn(d, z));
}

// ---------------- kernel 1: classify rays, SH encode, compact ----------------
__global__ __launch_bounds__(64)
void k_classify(const float* __restrict__ rays,
                float* __restrict__ sh,
                unsigned* __restrict__ counter,
                unsigned* __restrict__ rbase,
                unsigned* __restrict__ rn,
                unsigned* __restrict__ plist) {
  int r = blockIdx.x * 64 + threadIdx.x;
  if (r >= NRAYS) return;
  float ox = rays[6*r+0], oy = rays[6*r+1], oz = rays[6*r+2];
  float dx = rays[6*r+3], dy = rays[6*r+4], dz = rays[6*r+5];
  float x = dx, y = dy, z = dz;
  float xx = x*x, yy = y*y, zz = z*z, xy = x*y, yz = y*z, xz = x*z;
  float* shp = sh + 16*r;
  shp[0]  = 0.28209479177387814f;
  shp[1]  = -0.4886025119029199f * y;
  shp[2]  =  0.4886025119029199f * z;
  shp[3]  = -0.4886025119029199f * x;
  shp[4]  =  1.0925484305920792f * xy;
  shp[5]  = -1.0925484305920792f * yz;
  shp[6]  =  0.31539156525252005f * (2.0f*zz - xx - yy);
  shp[7]  = -1.0925484305920792f * xz;
  shp[8]  =  0.5462742152960396f * (xx - yy);
  shp[9]  = -0.5900435899266435f * y * (3.0f*xx - yy);
  shp[10] =  2.890611442640554f  * xy * z;
  shp[11] = -0.4570457994644658f * y * (4.0f*zz - xx - yy);
  shp[12] =  0.3731763325901154f * z * (2.0f*zz - 3.0f*xx - 3.0f*yy);
  shp[13] = -0.4570457994644658f * x * (4.0f*zz - xx - yy);
  shp[14] =  1.445305721320277f  * z * (xx - yy);
  shp[15] = -0.5900435899266435f * x * (xx - 3.0f*yy);
  // fp32 in-box prefix count (box convex, o inside => in-box samples are a prefix)
  int n = 0;
  for (int i = 0; i < 128; ++i) {
    float zi = zval32(i);
    float px = pcoord(ox, dx, zi);
    float py = pcoord(oy, dy, zi);
    float pz = pcoord(oz, dz, zi);
    bool in = (px >= -1.5f) && (px <= 1.5f) && (py >= -1.5f) && (py <= 1.5f)
           && (pz >= -1.5f) && (pz <= 1.5f);
    if (!in) break;
    ++n;
  }
  unsigned base = atomicAdd(counter, (unsigned)n);
  rbase[r] = base;
  rn[r]    = (unsigned)n;
  for (int i = 0; i < n; ++i) plist[base + i] = (unsigned)(r*128 + i);
}

// ---------------- kernel 2: cooperative tile MLP ----------------
// 64 points/tile, 8 waves/block; wave q computes outputs [jbase, jbase+JC) for
// all 64 points. Weight addresses wave-uniform (jbase via readfirstlane) -> s_load.
// act layout [k*64+p]: lanes read consecutive addresses -> conflict-free.
// FMA accumulation order (k ascending per output) identical to the validated kernel.
template<int IN, int TOTOUT, int JC, bool RELU>
__device__ __forceinline__ void layer(const float* __restrict__ W, int jbase,
                                      const float* __restrict__ in,
                                      float* __restrict__ out, int lane) {
  float acc[JC];
#pragma unroll
  for (int j = 0; j < JC; ++j) acc[j] = 0.0f;
#pragma unroll 4
  for (int k = 0; k < IN; ++k) {
    float a = in[k*64 + lane];
    const float* Wk = W + k*TOTOUT + jbase;
#pragma unroll
    for (int j = 0; j < JC; ++j) acc[j] = fmaf(a, Wk[j], acc[j]);
  }
#pragma unroll
  for (int j = 0; j < JC; ++j)
    out[(jbase + j)*64 + lane] = RELU ? fmaxf(acc[j], 0.0f) : acc[j];
}

__global__ __launch_bounds__(MBLK)
void k_mlp(const float* __restrict__ rays,
           const float* __restrict__ tables,
           const float* __restrict__ w_s0, const float* __restrict__ w_s1,
           const float* __restrict__ w_s2, const float* __restrict__ w_c0,
           const float* __restrict__ w_c1, const float* __restrict__ w_c2,
           const float* __restrict__ w_c3,
           const float* __restrict__ sh,
           const unsigned* __restrict__ counter,
           const unsigned* __restrict__ plist,
           float4* __restrict__ results) {
  __shared__ float bufA[64*64];
  __shared__ float bufB[64*64];
  __shared__ float sig_s[64];
  __shared__ unsigned pid_s[64];
  const int t = threadIdx.x;
  const int lane = t & 63;
  const int q = __builtin_amdgcn_readfirstlane(t >> 6);   // wave id 0..7
  const unsigned count = *counter;
  const unsigned ntiles = (count + 63u) >> 6;
  const float RESF[NLEV] = {16.f,20.f,25.f,32.f,40.f,50.f,64.f,80.f,
                            101.f,128.f,161.f,203.f,256.f,322.f,406.f,512.f};
  for (unsigned tile = blockIdx.x; tile < ntiles; tile += MGRID) {
    unsigned s0 = tile << 6;
    if (t < 64) {
      unsigned s = s0 + (unsigned)t;
      pid_s[t] = (s < count) ? plist[s] : 0u;
    }
    __syncthreads();
    // ---- hash gather: wave q handles levels 2q, 2q+1 -> rows 4q..4q+3 ----
    {
      unsigned pid = pid_s[lane];
      int r = (int)(pid >> 7);
      int i = (int)(pid & 127u);
      float zi = zval32(i);
      float px = pcoord(rays[6*r+0], rays[6*r+3], zi);
      float py = pcoord(rays[6*r+1], rays[6*r+4], zi);
      float pz = pcoord(rays[6*r+2], rays[6*r+5], zi);
      float xcx = fminf(fmaxf(px, -1.5f), 1.5f);
      float xcy = fminf(fmaxf(py, -1.5f), 1.5f);
      float xcz = fminf(fmaxf(pz, -1.5f), 1.5f);
#pragma unroll
      for (int li = 0; li < 2; ++li) {
        int l = 2*q + li;
        const float grid = 3.0f / RESF[l];
        float bfx = floorf(__fdiv_rn(__fadd_rn(xcx, 1.5f), grid));
        float bfy = floorf(__fdiv_rn(__fadd_rn(xcy, 1.5f), grid));
        float bfz = floorf(__fdiv_rn(__fadd_rn(xcz, 1.5f), grid));
        float vmx = __fadd_rn(__fmul_rn(bfx, grid), -1.5f);
        float vmy = __fadd_rn(__fmul_rn(bfy, grid), -1.5f);
        float vmz = __fadd_rn(__fmul_rn(bfz, grid), -1.5f);
        float wx = __fdiv_rn(__fsub_rn(xcx, vmx), grid);
        float wy = __fdiv_rn(__fsub_rn(xcy, vmy), grid);
        float wz = __fdiv_rn(__fsub_rn(xcz, vmz), grid);
        unsigned cx0 = (unsigned)(int)bfx, cy0 = (unsigned)(int)bfy, cz0 = (unsigned)(int)bfz;
        unsigned cx1 = cx0 + 1u, cy1 = cy0 + 1u, cz1 = cz0 + 1u;
        unsigned hy0 = cy0*2654435761u, hy1 = cy1*2654435761u;
        unsigned hz0 = cz0*805459861u,  hz1 = cz1*805459861u;
        const float2* tb = (const float2*)tables + (size_t)l*THASH;
        float2 e000 = tb[(cx0^hy0^hz0)&(THASH-1)];
        float2 e001 = tb[(cx0^hy0^hz1)&(THASH-1)];
        float2 e010 = tb[(cx0^hy1^hz0)&(THASH-1)];
        float2 e011 = tb[(cx0^hy1^hz1)&(THASH-1)];
        float2 e100 = tb[(cx1^hy0^hz0)&(THASH-1)];
        float2 e101 = tb[(cx1^hy0^hz1)&(THASH-1)];
        float2 e110 = tb[(cx1^hy1^hz0)&(THASH-1)];
        float2 e111 = tb[(cx1^hy1^hz1)&(THASH-1)];
        float iwx = 1.f-wx, iwy = 1.f-wy, iwz = 1.f-wz;
        float c00a = e000.x*iwx + e100.x*wx, c00b = e000.y*iwx + e100.y*wx;
        float c01a = e001.x*iwx + e101.x*wx, c01b = e001.y*iwx + e101.y*wx;
        float c10a = e010.x*iwx + e110.x*wx, c10b = e010.y*iwx + e110.y*wx;
        float c11a = e011.x*iwx + e111.x*wx, c11b = e011.y*iwx + e111.y*wx;
        float c0a = c00a*iwy + c10a*wy, c0b = c00b*iwy + c10b*wy;
        float c1a = c01a*iwy + c11a*wy, c1b = c01b*iwy + c11b*wy;
        bufA[(2*l+0)*64 + lane] = c0a*iwz + c1a*wz;
        bufA[(2*l+1)*64 + lane] = c0b*iwz + c1b*wz;
      }
    }
    __syncthreads();
    layer<32,64,8,true >(w_s0, q*8, bufA, bufB, lane); __syncthreads();
    layer<64,64,8,true >(w_s1, q*8, bufB, bufA, lane); __syncthreads();
    layer<64,16,2,false>(w_s2, q*2, bufA, bufB, lane); __syncthreads();
    if (q == 0) sig_s[lane] = bufB[0*64 + lane];
    // assemble color input into bufA: rows 0..15 = SH, rows 16..30 = geo (bufB rows 1..15)
    for (int idx = t; idx < 31*64; idx += MBLK) {
      int k = idx >> 6, p = idx & 63;
      float v;
      if (k < 16) v = sh[(pid_s[p] >> 7)*16 + k];
      else        v = bufB[(k-15)*64 + p];
      bufA[idx] = v;
    }
    __syncthreads();
    layer<31,64,8,true >(w_c0, q*8, bufA, bufB, lane); __syncthreads();
    layer<64,64,8,true >(w_c1, q*8, bufB, bufA, lane); __syncthreads();
    layer<64,64,8,true >(w_c2, q*8, bufA, bufB, lane); __syncthreads();
    if (q < 3) layer<64,3,1,false>(w_c3, q, bufB, bufA, lane);
    __syncthreads();
    if (q == 0) {
      unsigned s = s0 + (unsigned)lane;
      if (s < count) {
        float4 res;
        res.x = sig_s[lane];
        res.y = bufA[0*64 + lane];
        res.z = bufA[1*64 + lane];
        res.w = bufA[2*64 + lane];
        results[s] = res;
      }
    }
    __syncthreads();
  }
}

// ---------------- kernel 3: composite, fp32 with expm1f ----------------
// alpha = -expm1f(-x) keeps RELATIVE precision at x~3e-6 (the R2 failure was
// 1-expf(-x) cancellation); log-amplified loss error stays ~1e-9.
__global__ __launch_bounds__(64)
void k_comp(const float* __restrict__ rays,
            const unsigned* __restrict__ rbase,
            const unsigned* __restrict__ rn,
            const float4* __restrict__ results,
            float* __restrict__ out) {
  int r = blockIdx.x * 64 + threadIdx.x;
  if (r >= NRAYS) return;
  float dx = rays[6*r+3], dy = rays[6*r+4], dz = rays[6*r+5];
  float dnorm = sqrtf(dx*dx + dy*dy + dz*dz);
  int n = (int)rn[r];
  unsigned base = rbase[r];
  const float step = 4.0f/127.0f;
  const float diststep = __fmul_rn(step, dnorm);   // n<=47<127: never the 1e10 tail
  float S = 0.f, ch0 = 0.f, ch1 = 0.f, ch2 = 0.f, dep = 0.f, trans = 1.f;
  for (int i = 0; i < n; ++i) {
    float4 rs = results[base + i];
    float z = zval32(i);
    float sg = fmaxf(rs.x, 0.f);
    float alpha = -expm1f(-__fmul_rn(sg, diststep));
    float w = __fmul_rn(alpha, trans);
    trans = __fmul_rn(trans, __fadd_rn(__fsub_rn(1.f, alpha), 1e-10f));
    float s0 = 1.f/(1.f + expf(-rs.y));
    float s1 = 1.f/(1.f + expf(-rs.z));
    float s2 = 1.f/(1.f + expf(-rs.w));
    S += w; ch0 += w*s0; ch1 += w*s1; ch2 += w*s2; dep += w*z;
  }
  float rem  = __fadd_rn(__fsub_rn(1.f, S), 1e-6f);
  float Stot = __fadd_rn(S, rem);
  float loss = 0.f, trans2 = 1.f;
  for (int i = 0; i < n; ++i) {
    float4 rs = results[base + i];
    float sg = fmaxf(rs.x, 0.f);
    float alpha = -expm1f(-__fmul_rn(sg, diststep));
    float w = __fmul_rn(alpha, trans2);
    trans2 = __fmul_rn(trans2, __fadd_rn(__fsub_rn(1.f, alpha), 1e-10f));
    float p = __fdiv_rn(w, Stot);
    loss += p * logf(fmaxf(p, 1e-37f));
  }
  float pl = __fdiv_rn(rem, Stot);
  loss += pl * logf(fmaxf(pl, 1e-37f));
  out[3*r+0] = ch0; out[3*r+1] = ch1; out[3*r+2] = ch2;
  out[3*NRAYS + r] = dep;
  out[4*NRAYS + r] = -loss;
}

// ---------------- launch ----------------
extern "C" void kernel_launch(void* const* d_in, const int* in_sizes, int n_in,
                              void* d_out, int out_size, void* d_ws, size_t ws_size,
                              hipStream_t stream) {
  const float* rays   = (const float*)d_in[0];
  const float* tables = (const float*)d_in[1];
  const float* ws0    = (const float*)d_in[2];
  const float* ws1    = (const float*)d_in[3];
  const float* ws2    = (const float*)d_in[4];
  const float* wc0    = (const float*)d_in[5];
  const float* wc1    = (const float*)d_in[6];
  const float* wc2    = (const float*)d_in[7];
  const float* wc3    = (const float*)d_in[8];

  char* ws = (char*)d_ws;
  unsigned* counter = (unsigned*)ws;
  unsigned* rbase   = (unsigned*)(ws + 256);
  unsigned* rn      = (unsigned*)(ws + 256 + 65536);
  float*    sh      = (float*)  (ws + 256 + 131072);
  float4*   results = (float4*) (ws + 1179904);
  unsigned* plist   = (unsigned*)(ws + 1179904 + (size_t)MAXPTS*16);

  hipMemsetAsync(counter, 0, 4, stream);
  k_classify<<<NRAYS/64, 64, 0, stream>>>(rays, sh, counter, rbase, rn, plist);
  k_mlp<<<MGRID, MBLK, 0, stream>>>(rays, tables, ws0, ws1, ws2,
                                    wc0, wc1, wc2, wc3, sh, counter, plist, results);
  k_comp<<<NRAYS/64, 64, 0, stream>>>(rays, rbase, rn, results, (float*)d_out);
}